// Round 5
// baseline (478.576 us; speedup 1.0000x reference)
//
#include <hip/hip_runtime.h>

// Problem constants (from reference)
#define B_      128
#define NPIX    32      // N = M = 32
#define NNEO    30      // N-2
#define NCH     19      // state channels (channel-planar layout)
#define PLANE   1024    // 32*32 floats per channel plane
#define OUTD    21      // OUT_DIM
#define ITERS   10
#define THRESHV 0.0007f
#define HSTRIDE 31      // s_h cell stride: gcd(31,32)=1 -> conflict-free

#define STATE_ELEMS (B_ * NCH * PLANE)             // 2,490,368 floats per buffer
#define NCELLS      (B_ * NNEO * NNEO)             // 115,200
#define CLASS_ELEMS (NCELLS * 3)                   // 345,600

// ---------------------------------------------------------------------------
// R15: CHANNEL-PLANAR state + coalesced global fv loads, no state LDS.
// R14 post-mortem: VALU floor 10.3 us/step but steps ran ~33-43 us. Stalls =
// 5.3 us/step LDS bank conflicts (CPAD=20 -> 8-way aliasing on ds_read_b128)
// + lgkmcnt coupling (fv ds_read and weight s_load share lgkmcnt -> every fv
// use drains the weight prefetch queue) + staging + 4 barriers.
// This version: state stored [b][ch][32][32]; consecutive cells = consecutive
// addresses -> fv loads are coalesced global_load_dword on vmcnt, fully
// decoupled from the s_load weight stream (lgkmcnt = weights only). fv loads
// 2-deep software-pipelined (statically-indexed struct; load patch p+1 while
// computing patch p). LDS = double-buffered s_h only (barriers 4 -> 2, zero
// bank conflicts). 900 blocks x 256 threads = 128 cells x 2 halves, exact.
// Accumulation order identical to R14 (bias, patches (pr,pc) asc, img row,
// ch rows asc, pos rows; L2/L3 k ascending) -> numerics match.
// MODE: 0 = first step (state==0, perc=identity), 1 = mid, 2 = last.
// ---------------------------------------------------------------------------

__global__ void nca_init(float* __restrict__ stateA, float* __restrict__ stateB) {
    int idx = blockIdx.x * blockDim.x + threadIdx.x;
    const int total = B_ * 124 * NCH;
    if (idx >= total) return;
    int c  = idx % NCH;
    int t2 = idx / NCH;
    int cellp = t2 % 124;
    int b    = t2 / 124;
    int i, j;
    if (cellp < 32)      { i = 0;  j = cellp; }
    else if (cellp < 64) { i = 31; j = cellp - 32; }
    else { int k = cellp - 64; i = 1 + (k >> 1); j = (k & 1) ? 31 : 0; }
    size_t off = ((size_t)(b * NCH + c)) * PLANE + i * NPIX + j;
    stateA[off] = 0.0f;
    stateB[off] = 0.0f;
}

#define ROW15(A, x, wrp) do { const float xx_ = (x); \
    const float* __restrict__ w_ = (wrp); \
    _Pragma("unroll") for (int o_ = 0; o_ < 15; o_++) (A)[o_] += xx_ * w_[o_]; \
} while (0)

#define ROW12(A, x, wrp) do { const float xx_ = (x); \
    const float* __restrict__ w_ = (wrp); \
    _Pragma("unroll") for (int o_ = 0; o_ < 12; o_++) (A)[o_] += xx_ * w_[o_]; \
} while (0)

#define ROW9(A, x, wrp) do { const float xx_ = (x); \
    const float* __restrict__ w_ = (wrp); \
    _Pragma("unroll") for (int o_ = 0; o_ < 9; o_++) (A)[o_] += xx_ * w_[o_]; \
} while (0)

// One perception point: 19 state channels + 1 image value. All indices are
// compile-time after inlining -> stays in registers (rule #20).
struct P20 { float c[NCH]; float iv; };

__device__ __forceinline__ P20 loadp(const float* __restrict__ sb,
                                     const float* __restrict__ ib,
                                     int i, int j, int px, int py,
                                     int pr, int pc) {
    P20 p;
    const int poff = (i + pr) * NPIX + (j + pc);
#pragma unroll
    for (int ch = 0; ch < NCH; ch++) p.c[ch] = sb[ch * PLANE + poff];
    p.iv = ib[(px + pr) * NPIX + (py + pc)];
    return p;
}

__device__ __forceinline__ void fmap15(float* acc, const P20& p,
                                       const float* __restrict__ wp) {
    ROW15(acc, p.iv, wp);                              // row 0: image
#pragma unroll
    for (int ch = 0; ch < NCH; ch++)                   // rows 1..19: state
        ROW15(acc, p.c[ch], wp + (ch + 1) * 30);
}

template<int MODE>
__global__ __launch_bounds__(256, 4)
void nca_step(const float* __restrict__ img,
              const float* __restrict__ W1, const float* __restrict__ b1,
              const float* __restrict__ W2, const float* __restrict__ b2,
              const float* __restrict__ W3, const float* __restrict__ b3,
              const float* __restrict__ state_old, float* __restrict__ state_new,
              int* perc, float* __restrict__ guesses_out,
              float* __restrict__ class_out)
{
    __shared__ float s_h[2][128 * HSTRIDE];            // 2 x 15.9 KB

    const int tid  = threadIdx.x;
    const int h    = __builtin_amdgcn_readfirstlane(tid >> 7); // wave-uniform
    const int cl   = tid & 127;
    const int cell = blockIdx.x * 128 + cl;            // < NCELLS exactly
    const int qoff = h * 15;

    const int b  = cell / (NNEO * NNEO);
    const int ij = cell - b * (NNEO * NNEO);
    const int i  = ij / NNEO;
    const int j  = ij - i * NNEO;

    int px, py;
    if (MODE == 0) { px = i; py = j; }
    else           { px = perc[2 * cell]; py = perc[2 * cell + 1]; }

    const float* __restrict__ sb = state_old + (size_t)b * (NCH * PLANE);
    const float* __restrict__ ib = img + (size_t)b * PLANE;

    // ---------------- layer 1: 182 -> 30 (this thread: 15 @ qoff) ----------
    float a1[15];
    {
        float acc[15];
#pragma unroll
        for (int o = 0; o < 15; o++) acc[o] = b1[qoff + o];

        if (MODE == 0) {
#pragma clang loop unroll(disable)
            for (int pr = 0; pr < 3; pr++) {
#pragma clang loop unroll(disable)
                for (int pc = 0; pc < 3; pc++) {
                    const float iv = ib[(px + pr) * NPIX + (py + pc)];
                    ROW15(acc, iv, W1 + (pr * 3 + pc) * 600 + qoff);
                }
            }
        } else {
            // 2-deep software-pipelined: load patch p+1 while computing p.
            P20 pa = loadp(sb, ib, i, j, px, py, 0, 0);
            P20 pb = loadp(sb, ib, i, j, px, py, 0, 1);
            fmap15(acc, pa, W1 + 0 * 600 + qoff);
            pa = loadp(sb, ib, i, j, px, py, 0, 2);
            fmap15(acc, pb, W1 + 1 * 600 + qoff);
            pb = loadp(sb, ib, i, j, px, py, 1, 0);
            fmap15(acc, pa, W1 + 2 * 600 + qoff);
            pa = loadp(sb, ib, i, j, px, py, 1, 1);
            fmap15(acc, pb, W1 + 3 * 600 + qoff);
            pb = loadp(sb, ib, i, j, px, py, 1, 2);
            fmap15(acc, pa, W1 + 4 * 600 + qoff);
            pa = loadp(sb, ib, i, j, px, py, 2, 0);
            fmap15(acc, pb, W1 + 5 * 600 + qoff);
            pb = loadp(sb, ib, i, j, px, py, 2, 1);
            fmap15(acc, pa, W1 + 6 * 600 + qoff);
            pa = loadp(sb, ib, i, j, px, py, 2, 2);
            fmap15(acc, pb, W1 + 7 * 600 + qoff);
            fmap15(acc, pa, W1 + 8 * 600 + qoff);
        }
        const float posx = (float)(px - 16) * 0.0625f;
        const float posy = (float)(py - 16) * 0.0625f;
        ROW15(acc, posx, W1 + 180 * 30 + qoff);
        ROW15(acc, posy, W1 + 181 * 30 + qoff);
#pragma unroll
        for (int o = 0; o < 15; o++) a1[o] = fmaxf(acc[o], 0.0f);
#pragma unroll
        for (int o = 0; o < 15; o++) s_h[0][cl * HSTRIDE + qoff + o] = a1[o];
    }
    __syncthreads();                                   // B1: a1 visible

    // ---------------- layer 2: 30 -> 30 (this thread: 15 @ qoff) -----------
    float h2[15];
    {
        float acc[15];
#pragma unroll
        for (int o = 0; o < 15; o++) acc[o] = b2[qoff + o];
        if (h == 0) {
#pragma unroll
            for (int k = 0; k < 15; k++)
                ROW15(acc, a1[k], W2 + k * 30);
#pragma clang loop unroll(disable)
            for (int k = 15; k < 30; k++) {
                const float x = s_h[0][cl * HSTRIDE + k];
                ROW15(acc, x, W2 + k * 30);
            }
        } else {
#pragma clang loop unroll(disable)
            for (int k = 0; k < 15; k++) {
                const float x = s_h[0][cl * HSTRIDE + k];
                ROW15(acc, x, W2 + k * 30 + 15);
            }
#pragma unroll
            for (int k = 0; k < 15; k++)
                ROW15(acc, a1[k], W2 + (k + 15) * 30 + 15);
        }
#pragma unroll
        for (int o = 0; o < 15; o++) h2[o] = fmaxf(acc[o], 0.0f);
#pragma unroll
        for (int o = 0; o < 15; o++) s_h[1][cl * HSTRIDE + qoff + o] = h2[o];
    }
    __syncthreads();                                   // B2: h2 visible

    // ---------------- layer 3: 30 -> 21 (h0: cols 0-11, h1: cols 12-20) ----
    const int cen = (i + 1) * NPIX + (j + 1);
    if (h == 0) {
        float ov[12];
#pragma unroll
        for (int c = 0; c < 12; c++) ov[c] = b3[c];
#pragma unroll
        for (int k = 0; k < 15; k++)
            ROW12(ov, h2[k], W3 + k * 21);
#pragma clang loop unroll(disable)
        for (int k = 15; k < 30; k++) {
            const float x = s_h[1][cl * HSTRIDE + k];
            ROW12(ov, x, W3 + k * 21);
        }
        if (MODE == 2) {
            float* __restrict__ g = guesses_out + (size_t)cell * OUTD;
#pragma unroll
            for (int c = 0; c < 12; c++) g[c] = ov[c];
        } else {
            float* __restrict__ sn = state_new + (size_t)b * (NCH * PLANE) + cen;
            const float* __restrict__ so = sb + cen;
            if (MODE == 0) {
#pragma unroll
                for (int c = 0; c < 12; c++) sn[c * PLANE] = ov[c];
            } else {
#pragma unroll
                for (int c = 0; c < 12; c++) sn[c * PLANE] = so[c * PLANE] + ov[c];
            }
        }
    } else {
        float ov[9];                                   // global cols 12..20
#pragma unroll
        for (int c = 0; c < 9; c++) ov[c] = b3[12 + c];
#pragma clang loop unroll(disable)
        for (int k = 0; k < 15; k++) {
            const float x = s_h[1][cl * HSTRIDE + k];
            ROW9(ov, x, W3 + k * 21 + 12);
        }
#pragma unroll
        for (int k = 0; k < 15; k++)
            ROW9(ov, h2[k], W3 + (k + 15) * 21 + 12);
        if (MODE == 2) {
            float* __restrict__ g = guesses_out + (size_t)cell * OUTD;
#pragma unroll
            for (int c = 0; c < 9; c++) g[12 + c] = ov[c];
            float* __restrict__ cs = class_out + (size_t)cell * 3;
#pragma unroll
            for (int cc = 0; cc < 3; cc++)
                cs[cc] = sb[(16 + cc) * PLANE + cen] + ov[4 + cc];
        } else {
            float* __restrict__ sn = state_new + (size_t)b * (NCH * PLANE) + cen;
            const float* __restrict__ so = sb + cen;
            if (MODE == 0) {
#pragma unroll
                for (int c = 0; c < 7; c++) sn[(12 + c) * PLANE] = ov[c];
            } else {
#pragma unroll
                for (int c = 0; c < 7; c++)
                    sn[(12 + c) * PLANE] = so[(12 + c) * PLANE] + ov[c];
            }
            int dxm = (ov[7] > THRESHV) ? 1 : ((ov[7] < -THRESHV) ? -1 : 0);
            int dym = (ov[8] > THRESHV) ? 1 : ((ov[8] < -THRESHV) ? -1 : 0);
            px += dxm; py += dym;
            px = (px < 0) ? 0 : ((px > NNEO - 1) ? NNEO - 1 : px);
            py = (py < 0) ? 0 : ((py > NNEO - 1) ? NNEO - 1 : py);
            perc[2 * cell + 0] = px;
            perc[2 * cell + 1] = py;
        }
    }
}

extern "C" void kernel_launch(void* const* d_in, const int* in_sizes, int n_in,
                              void* d_out, int out_size, void* d_ws, size_t ws_size,
                              hipStream_t stream) {
    const float* img = (const float*)d_in[0];
    const float* W1  = (const float*)d_in[1];
    const float* b1  = (const float*)d_in[2];
    const float* W2  = (const float*)d_in[3];
    const float* b2  = (const float*)d_in[4];
    const float* W3  = (const float*)d_in[5];
    const float* b3  = (const float*)d_in[6];

    float* out = (float*)d_out;
    float* class_out   = out;                 // 345,600 floats
    float* guesses_out = out + CLASS_ELEMS;   // 2,419,200 floats

    float* stateA = (float*)d_ws;
    float* stateB = stateA + STATE_ELEMS;
    int*   perc   = (int*)(stateB + STATE_ELEMS);

    {
        const int total = B_ * 124 * NCH;
        nca_init<<<(total + 255) / 256, 256, 0, stream>>>(stateA, stateB);
    }

    const int grid = NCELLS / 128;            // 900 blocks, exact cover
    // t = 0: state==0, perc = identity; writes stateB + perc
    nca_step<0><<<grid, 256, 0, stream>>>(img, W1, b1, W2, b2, W3, b3,
                                          stateA, stateB, perc,
                                          guesses_out, class_out);
    // t = 1..8: ping-pong
    for (int t = 1; t < ITERS - 1; t++) {
        const float* so = (t & 1) ? stateB : stateA;
        float*       sn = (t & 1) ? stateA : stateB;
        nca_step<1><<<grid, 256, 0, stream>>>(img, W1, b1, W2, b2, W3, b3,
                                              so, sn, perc,
                                              guesses_out, class_out);
    }
    // t = 9 (odd): reads stateB, emits guesses + class only
    nca_step<2><<<grid, 256, 0, stream>>>(img, W1, b1, W2, b2, W3, b3,
                                          stateB, stateA, perc,
                                          guesses_out, class_out);
}

// Round 6
// 382.500 us; speedup vs baseline: 1.2512x; 1.2512x over previous
//
#include <hip/hip_runtime.h>

// Problem constants (from reference)
#define B_      128
#define NPIX    32      // N = M = 32
#define NNEO    30      // N-2
#define NCH     19      // state channels (channel-planar layout)
#define PLANE   1024    // 32*32 floats per channel plane (global)
#define SROWS   10      // max staged rows per block (nr+2)
#define SPLANE  (SROWS * NPIX)   // 320 floats per LDS channel plane
#define OUTD    21      // OUT_DIM
#define ITERS   10
#define THRESHV 0.0007f
#define HSTRIDE 31      // s_h cell stride: gcd(31,32)=1 -> conflict-free

#define STATE_ELEMS (B_ * NCH * PLANE)             // 2,490,368 floats per buffer
#define NCELLS      (B_ * NNEO * NNEO)             // 115,200
#define CLASS_ELEMS (NCELLS * 3)                   // 345,600

// ---------------------------------------------------------------------------
// R16 = R14 structure (the proven best: LDS-staged, half-split, 512-thread
// blocks, 2 blocks/CU) with the two measured defects fixed by ONE layout
// change: state is CHANNEL-PLANAR in global AND LDS.
//  - R14's 3.29M bank-conflict cycles came from the [row][col][20] interleave
//    (lane stride 80B, gcd(20,32)=4 -> 8-way conflict on ds_read_b128).
//    Planar fv reads are 19 ds_read_b32 with consecutive lane addresses ->
//    2 lanes/bank = free.
//  - R15 proved global-gather fv dies on unhidden VMEM latency (compiler
//    pins VGPR~52, won't pipeline); staging through LDS is mandatory.
//  - Staging planar->planar is float4-coalesced both sides; state writes and
//    read-modify stay per-plane coalesced.
// Accumulation order identical to R14 (bias, patches (pr,pc) asc, img row,
// ch rows ascending, pos rows; L2/L3 k ascending) -> numerics match.
// MODE: 0 = first step (state==0, perc=identity), 1 = mid, 2 = last.
// ---------------------------------------------------------------------------

__global__ void nca_init(float* __restrict__ stateA, float* __restrict__ stateB) {
    int idx = blockIdx.x * blockDim.x + threadIdx.x;
    const int total = B_ * 124 * NCH;
    if (idx >= total) return;
    int c  = idx % NCH;
    int t2 = idx / NCH;
    int cellp = t2 % 124;
    int b    = t2 / 124;
    int i, j;
    if (cellp < 32)      { i = 0;  j = cellp; }
    else if (cellp < 64) { i = 31; j = cellp - 32; }
    else { int k = cellp - 64; i = 1 + (k >> 1); j = (k & 1) ? 31 : 0; }
    size_t off = ((size_t)(b * NCH + c)) * PLANE + i * NPIX + j;
    stateA[off] = 0.0f;
    stateB[off] = 0.0f;
}

#define ROW15(A, x, wrp) do { const float xx_ = (x); \
    const float* __restrict__ w_ = (wrp); \
    _Pragma("unroll") for (int o_ = 0; o_ < 15; o_++) (A)[o_] += xx_ * w_[o_]; \
} while (0)

#define ROW12(A, x, wrp) do { const float xx_ = (x); \
    const float* __restrict__ w_ = (wrp); \
    _Pragma("unroll") for (int o_ = 0; o_ < 12; o_++) (A)[o_] += xx_ * w_[o_]; \
} while (0)

#define ROW9(A, x, wrp) do { const float xx_ = (x); \
    const float* __restrict__ w_ = (wrp); \
    _Pragma("unroll") for (int o_ = 0; o_ < 9; o_++) (A)[o_] += xx_ * w_[o_]; \
} while (0)

template<int MODE>
__global__ __launch_bounds__(512, 4)
void nca_step(const float* __restrict__ img,
              const float* __restrict__ W1, const float* __restrict__ b1,
              const float* __restrict__ W2, const float* __restrict__ b2,
              const float* __restrict__ W3, const float* __restrict__ b3,
              const float* __restrict__ state_old, float* __restrict__ state_new,
              int* perc, float* __restrict__ guesses_out,
              float* __restrict__ class_out)
{
    __shared__ float s_state[NCH * SPLANE];       // 19 x 320 = 24.3 KB planar
    __shared__ float s_img[NPIX * NPIX];          // 4 KB
    __shared__ float s_h[256 * HSTRIDE];          // 31.7 KB   (total 60 KB)

    const int b   = blockIdx.y;
    const int rg  = blockIdx.x;                   // 4 groups: rows {8,8,8,6}
    const int i0  = rg * 8;
    const int nr  = (rg == 3) ? 6 : 8;
    const int tid = threadIdx.x;
    const int h   = __builtin_amdgcn_readfirstlane(tid >> 8);  // wave-uniform half
    const int cell = tid & 255;
    const int qoff = h * 15;

    // ---- stage state rows [i0, i0+nr+2) planar, and the image -------------
    if (MODE != 0) {
        // global: plane stride 256 float4; LDS: plane stride 80 float4
        const float4* __restrict__ g4 = (const float4*)
            (state_old + (size_t)b * (NCH * PLANE) + i0 * NPIX);
        float4* s4 = (float4*)s_state;
        if (nr == 8) {        // 10 rows = 80 f4 per channel
            for (int t = tid; t < NCH * 80; t += 512) {
                const int ch = t / 80, rem = t - ch * 80;
                s4[ch * 80 + rem] = g4[ch * 256 + rem];
            }
        } else {              // 8 rows = 64 f4 per channel
            for (int t = tid; t < NCH * 64; t += 512) {
                const int ch = t / 64, rem = t - ch * 64;
                s4[ch * 80 + rem] = g4[ch * 256 + rem];
            }
        }
    }
    if (tid < 256)
        ((float4*)s_img)[tid] = ((const float4*)(img + (size_t)b * PLANE))[tid];
    __syncthreads();                              // B1

    const int cells = nr * NNEO;
    const bool active = cell < cells;

    int r = 0, j = 0, i = 0, gcell = 0, px = 0, py = 0;
    if (active) {
        r = cell / NNEO;
        j = cell - r * NNEO;
        i = i0 + r;
        gcell = (b * NNEO + i) * NNEO + j;
        if (MODE == 0) { px = i; py = j; }
        else           { px = perc[2 * gcell]; py = perc[2 * gcell + 1]; }
    }

    // ---------------- layer 1: 182 -> 30 (this thread: 15 @ qoff) ----------
    float a1[15];
    {
        float acc[15];
#pragma unroll
        for (int o = 0; o < 15; o++) acc[o] = b1[qoff + o];
        if (active) {
            if (MODE == 0) {
#pragma clang loop unroll(disable)
                for (int pr = 0; pr < 3; pr++) {
#pragma clang loop unroll(disable)
                    for (int pc = 0; pc < 3; pc++) {
                        const float iv = s_img[(px + pr) * NPIX + (py + pc)];
                        ROW15(acc, iv, W1 + (pr * 3 + pc) * 600 + qoff);
                    }
                }
            } else {
#pragma clang loop unroll(disable)
                for (int pr = 0; pr < 3; pr++) {
#pragma clang loop unroll(disable)
                    for (int pc = 0; pc < 3; pc++) {
                        const float iv = s_img[(px + pr) * NPIX + (py + pc)];
                        const float* __restrict__ wp =
                            W1 + (pr * 3 + pc) * 600 + qoff;
                        const int soff = (r + pr) * NPIX + (j + pc);
                        // 19 conflict-free ds_read_b32 (consecutive lane addrs)
                        float fv[NCH];
#pragma unroll
                        for (int ch = 0; ch < NCH; ch++)
                            fv[ch] = s_state[ch * SPLANE + soff];
                        ROW15(acc, iv, wp);            // row 0: image
#pragma unroll
                        for (int ch = 0; ch < NCH; ch++)
                            ROW15(acc, fv[ch], wp + (ch + 1) * 30);
                    }
                }
            }
            const float posx = (float)(px - 16) * 0.0625f;
            const float posy = (float)(py - 16) * 0.0625f;
            ROW15(acc, posx, W1 + 180 * 30 + qoff);
            ROW15(acc, posy, W1 + 181 * 30 + qoff);
        }
#pragma unroll
        for (int o = 0; o < 15; o++) a1[o] = fmaxf(acc[o], 0.0f);
        if (active) {
#pragma unroll
            for (int o = 0; o < 15; o++) s_h[cell * HSTRIDE + qoff + o] = a1[o];
        }
    }
    __syncthreads();                              // B2: a1 visible

    // ---------------- layer 2: 30 -> 30 (this thread: 15 @ qoff) -----------
    float h2[15];
    {
        float acc[15];
#pragma unroll
        for (int o = 0; o < 15; o++) acc[o] = b2[qoff + o];
        if (active) {
            if (h == 0) {
#pragma unroll
                for (int k = 0; k < 15; k++)
                    ROW15(acc, a1[k], W2 + k * 30);
#pragma clang loop unroll(disable)
                for (int k = 15; k < 30; k++) {
                    const float x = s_h[cell * HSTRIDE + k];
                    ROW15(acc, x, W2 + k * 30);
                }
            } else {
#pragma clang loop unroll(disable)
                for (int k = 0; k < 15; k++) {
                    const float x = s_h[cell * HSTRIDE + k];
                    ROW15(acc, x, W2 + k * 30 + 15);
                }
#pragma unroll
                for (int k = 0; k < 15; k++)
                    ROW15(acc, a1[k], W2 + (k + 15) * 30 + 15);
            }
        }
#pragma unroll
        for (int o = 0; o < 15; o++) h2[o] = fmaxf(acc[o], 0.0f);
    }
    __syncthreads();                              // B3: all a1 reads done
    if (active) {
#pragma unroll
        for (int o = 0; o < 15; o++) s_h[cell * HSTRIDE + qoff + o] = h2[o];
    }
    __syncthreads();                              // B4: h2 visible

    // ---------------- layer 3: 30 -> 21 (h0: cols 0-11, h1: cols 12-20) ----
    if (active) {
        const int cen  = (i + 1) * NPIX + (j + 1);    // global in-plane offset
        const int lcen = (r + 1) * NPIX + (j + 1);    // LDS in-plane offset
        float* __restrict__ snp =
            state_new + (size_t)b * (NCH * PLANE) + cen;
        if (h == 0) {
            float ov[12];
#pragma unroll
            for (int c = 0; c < 12; c++) ov[c] = b3[c];
#pragma unroll
            for (int k = 0; k < 15; k++)
                ROW12(ov, h2[k], W3 + k * 21);
#pragma clang loop unroll(disable)
            for (int k = 15; k < 30; k++) {
                const float x = s_h[cell * HSTRIDE + k];
                ROW12(ov, x, W3 + k * 21);
            }
            if (MODE == 2) {
                float* __restrict__ g = guesses_out + (size_t)gcell * OUTD;
#pragma unroll
                for (int c = 0; c < 12; c++) g[c] = ov[c];
            } else if (MODE == 0) {
#pragma unroll
                for (int c = 0; c < 12; c++) snp[c * PLANE] = ov[c];
            } else {
#pragma unroll
                for (int c = 0; c < 12; c++)
                    snp[c * PLANE] = s_state[c * SPLANE + lcen] + ov[c];
            }
        } else {
            float ov[9];                              // global cols 12..20
#pragma unroll
            for (int c = 0; c < 9; c++) ov[c] = b3[12 + c];
#pragma clang loop unroll(disable)
            for (int k = 0; k < 15; k++) {
                const float x = s_h[cell * HSTRIDE + k];
                ROW9(ov, x, W3 + k * 21 + 12);
            }
#pragma unroll
            for (int k = 0; k < 15; k++)
                ROW9(ov, h2[k], W3 + (k + 15) * 21 + 12);
            if (MODE == 2) {
                float* __restrict__ g = guesses_out + (size_t)gcell * OUTD;
#pragma unroll
                for (int c = 0; c < 9; c++) g[12 + c] = ov[c];
                float* __restrict__ cs = class_out + (size_t)gcell * 3;
#pragma unroll
                for (int cc = 0; cc < 3; cc++)
                    cs[cc] = s_state[(16 + cc) * SPLANE + lcen] + ov[4 + cc];
            } else {
                if (MODE == 0) {
#pragma unroll
                    for (int c = 0; c < 7; c++) snp[(12 + c) * PLANE] = ov[c];
                } else {
#pragma unroll
                    for (int c = 0; c < 7; c++)
                        snp[(12 + c) * PLANE] =
                            s_state[(12 + c) * SPLANE + lcen] + ov[c];
                }
                int dxm = (ov[7] > THRESHV) ? 1 : ((ov[7] < -THRESHV) ? -1 : 0);
                int dym = (ov[8] > THRESHV) ? 1 : ((ov[8] < -THRESHV) ? -1 : 0);
                px += dxm; py += dym;
                px = (px < 0) ? 0 : ((px > NNEO - 1) ? NNEO - 1 : px);
                py = (py < 0) ? 0 : ((py > NNEO - 1) ? NNEO - 1 : py);
                perc[2 * gcell + 0] = px;
                perc[2 * gcell + 1] = py;
            }
        }
    }
}

extern "C" void kernel_launch(void* const* d_in, const int* in_sizes, int n_in,
                              void* d_out, int out_size, void* d_ws, size_t ws_size,
                              hipStream_t stream) {
    const float* img = (const float*)d_in[0];
    const float* W1  = (const float*)d_in[1];
    const float* b1  = (const float*)d_in[2];
    const float* W2  = (const float*)d_in[3];
    const float* b2  = (const float*)d_in[4];
    const float* W3  = (const float*)d_in[5];
    const float* b3  = (const float*)d_in[6];

    float* out = (float*)d_out;
    float* class_out   = out;                 // 345,600 floats
    float* guesses_out = out + CLASS_ELEMS;   // 2,419,200 floats

    float* stateA = (float*)d_ws;
    float* stateB = stateA + STATE_ELEMS;
    int*   perc   = (int*)(stateB + STATE_ELEMS);

    {
        const int total = B_ * 124 * NCH;
        nca_init<<<(total + 255) / 256, 256, 0, stream>>>(stateA, stateB);
    }

    const dim3 grid(4, B_);                   // 512 blocks = 2/CU exactly
    // t = 0: state==0, perc = identity; writes stateB + perc
    nca_step<0><<<grid, 512, 0, stream>>>(img, W1, b1, W2, b2, W3, b3,
                                          stateA, stateB, perc,
                                          guesses_out, class_out);
    // t = 1..8: ping-pong
    for (int t = 1; t < ITERS - 1; t++) {
        const float* so = (t & 1) ? stateB : stateA;
        float*       sn = (t & 1) ? stateA : stateB;
        nca_step<1><<<grid, 512, 0, stream>>>(img, W1, b1, W2, b2, W3, b3,
                                              so, sn, perc,
                                              guesses_out, class_out);
    }
    // t = 9 (odd): reads stateB, emits guesses + class only
    nca_step<2><<<grid, 512, 0, stream>>>(img, W1, b1, W2, b2, W3, b3,
                                          stateB, stateA, perc,
                                          guesses_out, class_out);
}